// Round 8
// baseline (309.988 us; speedup 1.0000x reference)
//
#include <hip/hip_runtime.h>
#include <hip/hip_bf16.h>

typedef short short8 __attribute__((ext_vector_type(8)));
typedef float f32x4 __attribute__((ext_vector_type(4)));

#define MFMA32(a, b, c) __builtin_amdgcn_mfma_f32_16x16x32_bf16(a, b, c, 0, 0, 0)

#if __has_builtin(__builtin_amdgcn_exp2f)
#define EXP2F(x) __builtin_amdgcn_exp2f(x)
#else
#define EXP2F(x) exp2f(x)
#endif

// async global->LDS, 16B per lane; LDS dest = wave-uniform base + lane*16
#define GLL16(gp, lp) __builtin_amdgcn_global_load_lds(                                  \
    (__attribute__((address_space(1))) unsigned int*)(unsigned long long)(const void*)(gp), \
    (__attribute__((address_space(3))) unsigned int*)(lp), 16, 0, 0)

// fp32 -> bf16 RNE
__device__ __forceinline__ unsigned short f2b(float f) {
    union { float f; unsigned int u; } v;
    v.f = f;
    unsigned int u = v.u;
    return (unsigned short)((u + 0x7fffu + ((u >> 16) & 1u)) >> 16);
}

static __device__ __forceinline__ f32x4 max4(f32x4 x, f32x4 y) {
    f32x4 r;
    r[0] = fmaxf(x[0], y[0]); r[1] = fmaxf(x[1], y[1]);
    r[2] = fmaxf(x[2], y[2]); r[3] = fmaxf(x[3], y[3]);
    return r;
}

// ---------------- merged cvt: x (+mask +tile flags) and 4 weights ----------------
__global__ void cvt_all(const float* __restrict__ x,
                        const float* __restrict__ w0, const float* __restrict__ w1,
                        const float* __restrict__ w2, const float* __restrict__ w3,
                        unsigned short* __restrict__ xb, unsigned short* __restrict__ wb,
                        float* __restrict__ maskbuf, int* __restrict__ flagsbuf) {
    int blk = blockIdx.x;
    if (blk < 4096) {
        int i = blk * 256 + threadIdx.x;           // 0..1048575 float4s
        float4 v = ((const float4*)x)[i];
        ushort4 o;
        o.x = f2b(v.x); o.y = f2b(v.y); o.z = f2b(v.z); o.w = f2b(v.w);
        ((ushort4*)xb)[i] = o;
        if ((i & 255) == 0) {
            int tok = i >> 8;                      // 0..4095
            maskbuf[tok] = (v.x != 0.0f) ? 0.0f : -1e30f;
            if (v.x == 0.0f)                       // flag the 128-key tile
                atomicOr(&flagsbuf[(tok >> 11) * 16 + ((tok & 2047) >> 7)], 1);
        }
    } else {
        int wi = blk - 4096;
        int widx = wi >> 10;
        int i = (wi & 1023) * 256 + threadIdx.x;   // 0..262143 float4s
        const float* src = widx == 0 ? w0 : (widx == 1 ? w1 : (widx == 2 ? w2 : w3));
        float4 v = ((const float4*)src)[i];
        ushort4 o;
        o.x = f2b(v.x); o.y = f2b(v.y); o.z = f2b(v.z); o.w = f2b(v.w);
        ((ushort4*)(wb + ((size_t)widx << 20)))[i] = o;
    }
}

// fold softmax scale (Dh^-0.5) and log2(e) into Q so attn uses raw exp2
#define QSCALE (0.125f * 1.44269504088896341f)

// ---------------- fused QKV GEMM, dbuf, operand-swapped epilogues ----------------
// grid (24, 32): seg = blockIdx.x>>3 (0=Q,1=K,2=V).
// Q,K out: (B,H,T,64) bf16, Q pre-scaled. V out tiled:
// [combo][kb128][chunk16][d64][8keys]; key order within each 32-group:
// pos = q*8 + t*4 + i for key 16t+4q+i (PV B-frag order).
__global__ __launch_bounds__(256) void gemm_qkv(
        const unsigned short* __restrict__ A,
        const unsigned short* __restrict__ wq, const unsigned short* __restrict__ wk,
        const unsigned short* __restrict__ wv,
        const float* __restrict__ bq, const float* __restrict__ bk,
        const float* __restrict__ bv,
        unsigned short* __restrict__ qbuf, unsigned short* __restrict__ kbuf,
        unsigned short* __restrict__ vbuf) {
    __shared__ __attribute__((aligned(16))) unsigned short As[2][128 * 32];
    __shared__ __attribute__((aligned(16))) unsigned short Bs[2][128 * 32];
    int tid = threadIdx.x;
    int lane = tid & 63, wave = tid >> 6;
    int lane15 = lane & 15, quad = lane >> 4;
    int seg = blockIdx.x >> 3;
    int bn = (blockIdx.x & 7) * 128;
    int bm = blockIdx.y * 128;
    const unsigned short* Bw = seg == 0 ? wq : (seg == 1 ? wk : wv);
    const float* bias = seg == 0 ? bq : (seg == 1 ? bk : bv);
    int wm = (wave >> 1) * 64, wn = (wave & 1) * 64;

    f32x4 acc[4][4];
#pragma unroll
    for (int i = 0; i < 4; i++)
#pragma unroll
        for (int j = 0; j < 4; j++) acc[i][j] = (f32x4){0.f, 0.f, 0.f, 0.f};

    int arow = tid >> 2, acol = (tid & 3) * 8;
    const unsigned short* A0 = &A[(size_t)(bm + arow) * 1024 + acol];
    const unsigned short* A1 = A0 + (size_t)64 * 1024;
    const unsigned short* B0 = &Bw[(size_t)(bn + arow) * 1024 + acol];
    const unsigned short* B1 = B0 + (size_t)64 * 1024;

    GLL16(A0, &As[0][(size_t)tid * 8]);
    GLL16(A1, &As[0][(size_t)(tid + 256) * 8]);
    GLL16(B0, &Bs[0][(size_t)tid * 8]);
    GLL16(B1, &Bs[0][(size_t)(tid + 256) * 8]);

    // rows-operand (C rows = its index): weights for Q/K, activations for V
    int rb = (seg == 2) ? wm : wn;
    int cb = (seg == 2) ? wn : wm;

    for (int it = 0; it < 32; it++) {
        int cur = it & 1;
        __syncthreads();
        if (it < 31) {
            int kn = (it + 1) * 32;
            GLL16(A0 + kn, &As[cur ^ 1][(size_t)tid * 8]);
            GLL16(A1 + kn, &As[cur ^ 1][(size_t)(tid + 256) * 8]);
            GLL16(B0 + kn, &Bs[cur ^ 1][(size_t)tid * 8]);
            GLL16(B1 + kn, &Bs[cur ^ 1][(size_t)(tid + 256) * 8]);
        }
        const unsigned short* rs = (seg == 2) ? As[cur] : Bs[cur];
        const unsigned short* cs = (seg == 2) ? Bs[cur] : As[cur];
        short8 rf[4], cf[4];
#pragma unroll
        for (int i = 0; i < 4; i++)
            rf[i] = *(const short8*)&rs[(rb + i * 16 + lane15) * 32 + quad * 8];
#pragma unroll
        for (int j = 0; j < 4; j++)
            cf[j] = *(const short8*)&cs[(cb + j * 16 + lane15) * 32 + quad * 8];
#pragma unroll
        for (int i = 0; i < 4; i++)
#pragma unroll
            for (int j = 0; j < 4; j++)
                acc[i][j] = MFMA32(rf[i], cf[j], acc[i][j]);
    }

    int bb = bm >> 11;
    if (seg == 2) {
        // rows = m (t), cols = n (d): lane has 4 consecutive t
#pragma unroll
        for (int j = 0; j < 4; j++) {
            int nl = bn + wn + j * 16 + lane15;
            int h = nl >> 6, d = nl & 63;
            float bv_ = bias[nl];
            size_t vbase = (size_t)(bb * 16 + h) * 131072;
#pragma unroll
            for (int i = 0; i < 4; i++) {
                int tk0 = (bm & 2047) + wm + i * 16 + quad * 4;
                int B7 = tk0 >> 7, g2 = (tk0 >> 5) & 3;
                ushort4 pk;
                pk.x = f2b(acc[i][j][0] + bv_);
                pk.y = f2b(acc[i][j][1] + bv_);
                pk.z = f2b(acc[i][j][2] + bv_);
                pk.w = f2b(acc[i][j][3] + bv_);
                size_t off = vbase + (size_t)(((B7 * 16 + g2 * 4 + quad) * 64 + d)) * 8
                             + (i & 1) * 4;
                *(ushort4*)&vbuf[off] = pk;
            }
        }
    } else {
        // rows = n (d), cols = m (t): lane has 4 consecutive d -> ushort4 along d
#pragma unroll
        for (int i = 0; i < 4; i++) {
            int n0 = bn + wn + i * 16 + quad * 4;
            int h = n0 >> 6, d0 = n0 & 63;
            f32x4 bv4 = *(const f32x4*)&bias[n0];
            unsigned short* dst = (seg == 0) ? qbuf : kbuf;
#pragma unroll
            for (int j = 0; j < 4; j++) {
                int m = bm + wm + j * 16 + lane15;
                int tk = m & 2047;
                f32x4 v = acc[i][j] + bv4;
                ushort4 pk;
                if (seg == 0) {
                    pk.x = f2b(v[0] * QSCALE); pk.y = f2b(v[1] * QSCALE);
                    pk.z = f2b(v[2] * QSCALE); pk.w = f2b(v[3] * QSCALE);
                } else {
                    pk.x = f2b(v[0]); pk.y = f2b(v[1]);
                    pk.z = f2b(v[2]); pk.w = f2b(v[3]);
                }
                *(ushort4*)&dst[((size_t)((bb * 16 + h) * 2048 + tk)) * 64 + d0] = pk;
            }
        }
    }
}

// ---------------- output projection GEMM: 64x128 tiles, dbuf, float4 stores ----------------
__global__ __launch_bounds__(256) void gemm_proj(
        const unsigned short* __restrict__ A, const unsigned short* __restrict__ Bw,
        const float* __restrict__ bias, float* __restrict__ out) {
    __shared__ __attribute__((aligned(16))) unsigned short As[2][64 * 32];
    __shared__ __attribute__((aligned(16))) unsigned short Bs[2][128 * 32];
    int tid = threadIdx.x;
    int lane = tid & 63, wave = tid >> 6;
    int lane15 = lane & 15, quad = lane >> 4;
    int bn = blockIdx.x * 128, bm = blockIdx.y * 64;
    int wm = (wave >> 1) * 32, wn = (wave & 1) * 64;

    f32x4 acc[4][2];
#pragma unroll
    for (int i = 0; i < 4; i++)
#pragma unroll
        for (int j = 0; j < 2; j++) acc[i][j] = (f32x4){0.f, 0.f, 0.f, 0.f};

    int arow = tid >> 2, acol = (tid & 3) * 8;
    const unsigned short* A0 = &A[(size_t)(bm + arow) * 1024 + acol];
    const unsigned short* B0 = &Bw[(size_t)(bn + arow) * 1024 + acol];
    const unsigned short* B1 = B0 + (size_t)64 * 1024;

    GLL16(A0, &As[0][(size_t)tid * 8]);
    GLL16(B0, &Bs[0][(size_t)tid * 8]);
    GLL16(B1, &Bs[0][(size_t)(tid + 256) * 8]);

    for (int it = 0; it < 32; it++) {
        int cur = it & 1;
        __syncthreads();
        if (it < 31) {
            int kn = (it + 1) * 32;
            GLL16(A0 + kn, &As[cur ^ 1][(size_t)tid * 8]);
            GLL16(B0 + kn, &Bs[cur ^ 1][(size_t)tid * 8]);
            GLL16(B1 + kn, &Bs[cur ^ 1][(size_t)(tid + 256) * 8]);
        }
        const unsigned short* as = As[cur];
        const unsigned short* bs = Bs[cur];
        short8 af[2], bf[4];
#pragma unroll
        for (int j = 0; j < 2; j++)
            af[j] = *(const short8*)&as[(wm + j * 16 + lane15) * 32 + quad * 8];
#pragma unroll
        for (int i = 0; i < 4; i++)
            bf[i] = *(const short8*)&bs[(wn + i * 16 + lane15) * 32 + quad * 8];
#pragma unroll
        for (int i = 0; i < 4; i++)
#pragma unroll
            for (int j = 0; j < 2; j++)
                acc[i][j] = MFMA32(bf[i], af[j], acc[i][j]);   // rows = n
    }

#pragma unroll
    for (int i = 0; i < 4; i++) {
        int n0 = bn + wn + i * 16 + quad * 4;
        f32x4 bv4 = *(const f32x4*)&bias[n0];
#pragma unroll
        for (int j = 0; j < 2; j++) {
            int m = bm + wm + j * 16 + lane15;
            f32x4 v = acc[i][j] + bv4;
            *(f32x4*)&out[(size_t)m * 1024 + n0] = v;
        }
    }
}

// ---------------- flash attention v8: split-K(2), 32 q/wave, 3 blocks/CU ----------------
// 1024 blocks: id = c_hi(2) | half(1) | qt(4) | c_lo(3). Same c_lo -> same XCD.
// Each block: 128 queries x 1024 keys. K in LDS (dbuf, 1 barrier/iter);
// V per-c register batches with one-batch lookahead. Partials: normalized O
// (bf16) + (m,l) fp32 per query; combine kernel merges the two halves.
__global__ __launch_bounds__(256, 3) void attn_kernel(
        const unsigned short* __restrict__ qbuf, const unsigned short* __restrict__ kbuf,
        const unsigned short* __restrict__ vtbuf, const float* __restrict__ maskbuf,
        const int* __restrict__ flagsbuf,
        unsigned short* __restrict__ o_part, float2* __restrict__ mlbuf) {
    __shared__ __attribute__((aligned(16))) unsigned short Ks[2][128 * 64];

    int id = blockIdx.x;
    int c_lo = id & 7;
    int qt = (id >> 3) & 15;
    int half = (id >> 7) & 1;
    int c_hi = id >> 8;
    int combo = c_lo | (c_hi << 3);
    int b = combo >> 4;
    int tid = threadIdx.x, lane = tid & 63, wave = tid >> 6;
    int lane15 = lane & 15, quad = lane >> 4;
    int q0 = qt * 128 + wave * 32;
    int kb0 = half * 1024;

    const unsigned short* Q  = qbuf  + (size_t)combo * 2048 * 64;
    const unsigned short* Kp = kbuf  + (size_t)combo * 2048 * 64;
    const unsigned short* Vt = vtbuf + (size_t)combo * 131072;   // tiled
    const float* mb = maskbuf + b * 2048;

    short8 qf[2][2];
#pragma unroll
    for (int a = 0; a < 2; a++)
#pragma unroll
        for (int g = 0; g < 2; g++)
            qf[a][g] = *(const short8*)&Q[(size_t)(q0 + a * 16 + lane15) * 64 + g * 32 + quad * 8];

    float m_run[2] = {-1e30f, -1e30f}, l_run[2] = {0.f, 0.f};
    f32x4 o[2][4];
#pragma unroll
    for (int a = 0; a < 2; a++)
#pragma unroll
        for (int c = 0; c < 4; c++) o[a][c] = (f32x4){0.f, 0.f, 0.f, 0.f};

    const f32x4 z4 = {0.f, 0.f, 0.f, 0.f};
    int x7 = lane15 & 7;

    // prologue: stage first K tile of this half
#pragma unroll
    for (int r4 = 0; r4 < 4; r4++) {
        int ci = tid + r4 * 256;
        int kr = ci >> 3, kc = (ci & 7) ^ (kr & 7);
        GLL16(&Kp[(size_t)(kb0 + kr) * 64 + kc * 8], &Ks[0][(size_t)ci * 8]);
    }

    for (int it = 0; it < 8; it++) {
        int cur = it & 1;
        int kb = kb0 + it * 128;
        __syncthreads();                       // K[cur] staged; prior-iter reads drained

        // ---- S^T = K.Q^T : 8 key-tiles x 2 q-tiles ----
        const unsigned short* ks = Ks[cur];
        f32x4 s[2][8];
#pragma unroll
        for (int t = 0; t < 8; t++) {
            int row = t * 16 + lane15;
            short8 k0 = *(const short8*)&ks[row * 64 + (quad ^ x7) * 8];
            short8 k1 = *(const short8*)&ks[row * 64 + ((quad + 4) ^ x7) * 8];
            s[0][t] = MFMA32(k1, qf[0][1], MFMA32(k0, qf[0][0], z4));
            s[1][t] = MFMA32(k1, qf[1][1], MFMA32(k0, qf[1][0], z4));
        }

        // ---- V batch c=0 (latency hidden under softmax) ----
        short8 vcur[4];
#pragma unroll
        for (int g = 0; g < 4; g++)
            vcur[g] = *(const short8*)&Vt[(size_t)((((half * 8 + it) * 16 + g * 4 + quad) * 64)
                                                   + lane15) * 8];

        // ---- prefetch next K tile ----
        if (it < 7) {
#pragma unroll
            for (int r4 = 0; r4 < 4; r4++) {
                int ci = tid + r4 * 256;
                int kr = ci >> 3, kc = (ci & 7) ^ (kr & 7);
                GLL16(&Kp[(size_t)(kb + 128 + kr) * 64 + kc * 8],
                      &Ks[cur ^ 1][(size_t)ci * 8]);
            }
        }

        // ---- mask add only when this 128-tile has masked keys (virtually never) ----
        if (flagsbuf[b * 16 + half * 8 + it]) {
#pragma unroll
            for (int t = 0; t < 8; t++) {
                f32x4 mkt = *(const f32x4*)&mb[kb + t * 16 + quad * 4];
                s[0][t] += mkt;
                s[1][t] += mkt;
            }
        }

        // ---- online softmax + pack P into MFMA32 B-frags ----
        short8 pb8[2][4];
#pragma unroll
        for (int a = 0; a < 2; a++) {
            f32x4 m01 = max4(s[a][0], s[a][1]), m23 = max4(s[a][2], s[a][3]);
            f32x4 m45 = max4(s[a][4], s[a][5]), m67 = max4(s[a][6], s[a][7]);
            f32x4 m4 = max4(max4(m01, m23), max4(m45, m67));
            float mx = fmaxf(fmaxf(m4[0], m4[1]), fmaxf(m4[2], m4[3]));
            mx = fmaxf(mx, __shfl_xor(mx, 16));
            mx = fmaxf(mx, __shfl_xor(mx, 32));
            float mnew = fmaxf(m_run[a], mx);
            float alpha = EXP2F(m_run[a] - mnew);
            m_run[a] = mnew;
            float ls = 0.f;
#pragma unroll
            for (int g = 0; g < 4; g++) {
                float e0 = EXP2F(s[a][2 * g][0] - mnew);
                float e1 = EXP2F(s[a][2 * g][1] - mnew);
                float e2 = EXP2F(s[a][2 * g][2] - mnew);
                float e3 = EXP2F(s[a][2 * g][3] - mnew);
                float f0 = EXP2F(s[a][2 * g + 1][0] - mnew);
                float f1 = EXP2F(s[a][2 * g + 1][1] - mnew);
                float f2 = EXP2F(s[a][2 * g + 1][2] - mnew);
                float f3 = EXP2F(s[a][2 * g + 1][3] - mnew);
                ls += ((e0 + e1) + (e2 + e3)) + ((f0 + f1) + (f2 + f3));
                union { uint4 u; short8 sv; } pu;   // bf16 truncation pack (P in [0,1])
                pu.u.x = __builtin_amdgcn_perm(__float_as_uint(e1), __float_as_uint(e0), 0x07060302u);
                pu.u.y = __builtin_amdgcn_perm(__float_as_uint(e3), __float_as_uint(e2), 0x07060302u);
                pu.u.z = __builtin_amdgcn_perm(__float_as_uint(f1), __float_as_uint(f0), 0x07060302u);
                pu.u.w = __builtin_amdgcn_perm(__float_as_uint(f3), __float_as_uint(f2), 0x07060302u);
                pb8[a][g] = pu.sv;
            }
            l_run[a] = l_run[a] * alpha + ls;
#pragma unroll
            for (int c = 0; c < 4; c++) o[a][c] *= alpha;
        }

        // ---- PV with one-batch V lookahead; each batch feeds both q-tiles ----
#pragma unroll
        for (int c = 0; c < 4; c++) {
            short8 vnext[4];
            if (c < 3) {
#pragma unroll
                for (int g = 0; g < 4; g++)
                    vnext[g] = *(const short8*)&Vt[(size_t)((((half * 8 + it) * 16 + g * 4 + quad) * 64)
                                                            + (c + 1) * 16 + lane15) * 8];
            }
#pragma unroll
            for (int g = 0; g < 4; g++) {
                o[0][c] = MFMA32(vcur[g], pb8[0][g], o[0][c]);
                o[1][c] = MFMA32(vcur[g], pb8[1][g], o[1][c]);
            }
#pragma unroll
            for (int g = 0; g < 4; g++) vcur[g] = vnext[g];
        }
    }

    // ---- epilogue: normalized partial O (bf16) + (m,l) ----
#pragma unroll
    for (int a = 0; a < 2; a++) {
        float l = l_run[a];
        l += __shfl_xor(l, 16);
        l += __shfl_xor(l, 32);
        float rl = 1.0f / l;
        int q = q0 + a * 16 + lane15;
        size_t base = ((size_t)(half * 32 + combo) * 2048 + q) * 64 + quad * 4;
#pragma unroll
        for (int c = 0; c < 4; c++) {
            ushort4 pk;
            pk.x = f2b(o[a][c][0] * rl);
            pk.y = f2b(o[a][c][1] * rl);
            pk.z = f2b(o[a][c][2] * rl);
            pk.w = f2b(o[a][c][3] * rl);
            *(ushort4*)&o_part[base + c * 16] = pk;
        }
        if (quad == 0)
            mlbuf[(size_t)(half * 32 + combo) * 2048 + q] = make_float2(m_run[a], l);
    }
}

// ---------------- combine split-K halves -> attnout (B,T,C) bf16 ----------------
__global__ __launch_bounds__(256) void combine_kernel(
        const unsigned short* __restrict__ o_part, const float2* __restrict__ mlbuf,
        unsigned short* __restrict__ attnout) {
    int e4 = blockIdx.x * 256 + threadIdx.x;   // 0..1048575 ushort4 units
    int d4 = e4 & 15;
    int q = (e4 >> 4) & 2047;
    int combo = e4 >> 15;
    int b = combo >> 4, h = combo & 15;

    float2 ml0 = mlbuf[(size_t)combo * 2048 + q];
    float2 ml1 = mlbuf[(size_t)(32 + combo) * 2048 + q];
    float M = fmaxf(ml0.x, ml1.x);
    float w0 = ml0.y * EXP2F(ml0.x - M);
    float w1 = ml1.y * EXP2F(ml1.x - M);
    float inv = 1.0f / (w0 + w1);
    w0 *= inv; w1 *= inv;

    ushort4 a0 = ((const ushort4*)o_part)[((size_t)combo * 2048 + q) * 16 + d4];
    ushort4 a1 = ((const ushort4*)o_part)[((size_t)(32 + combo) * 2048 + q) * 16 + d4];
    ushort4 pk;
    pk.x = f2b(w0 * __uint_as_float((unsigned)a0.x << 16) + w1 * __uint_as_float((unsigned)a1.x << 16));
    pk.y = f2b(w0 * __uint_as_float((unsigned)a0.y << 16) + w1 * __uint_as_float((unsigned)a1.y << 16));
    pk.z = f2b(w0 * __uint_as_float((unsigned)a0.z << 16) + w1 * __uint_as_float((unsigned)a1.z << 16));
    pk.w = f2b(w0 * __uint_as_float((unsigned)a0.w << 16) + w1 * __uint_as_float((unsigned)a1.w << 16));
    ((ushort4*)attnout)[((size_t)(b * 2048 + q) * 256) + h * 16 + d4] = pk;
}

extern "C" void kernel_launch(void* const* d_in, const int* in_sizes, int n_in,
                              void* d_out, int out_size, void* d_ws, size_t ws_size,
                              hipStream_t stream) {
    const float* x    = (const float*)d_in[0];
    const float* wq_w = (const float*)d_in[1];
    const float* wq_b = (const float*)d_in[2];
    const float* wk_w = (const float*)d_in[3];
    const float* wk_b = (const float*)d_in[4];
    const float* wv_w = (const float*)d_in[5];
    const float* wv_b = (const float*)d_in[6];
    const float* wo_w = (const float*)d_in[7];
    const float* wo_b = (const float*)d_in[8];
    float* out = (float*)d_out;

    char* ws = (char*)d_ws;
    size_t off = 0;
    unsigned short* xb      = (unsigned short*)(ws + off); off += (size_t)4096 * 1024 * 2;
    unsigned short* wb      = (unsigned short*)(ws + off); off += (size_t)4 * 1024 * 1024 * 2;
    unsigned short* qbuf    = (unsigned short*)(ws + off); off += (size_t)4096 * 1024 * 2;
    unsigned short* kbuf    = (unsigned short*)(ws + off); off += (size_t)4096 * 1024 * 2;
    unsigned short* vbuf    = (unsigned short*)(ws + off); off += (size_t)4096 * 1024 * 2;
    unsigned short* attnout = (unsigned short*)(ws + off); off += (size_t)4096 * 1024 * 2;
    unsigned short* o_part  = (unsigned short*)(ws + off); off += (size_t)2 * 32 * 2048 * 64 * 2;
    float2* mlbuf           = (float2*)(ws + off);         off += (size_t)2 * 32 * 2048 * 8;
    float* maskbuf          = (float*)(ws + off);          off += 4096 * 4;
    int* flagsbuf           = (int*)(ws + off);            off += 32 * 4;

    unsigned short* wqb = wb;
    unsigned short* wkb = wb + (1u << 20);
    unsigned short* wvb = wb + (2u << 20);
    unsigned short* wob = wb + (3u << 20);

    hipMemsetAsync(flagsbuf, 0, 32 * 4, stream);

    cvt_all<<<8192, 256, 0, stream>>>(x, wq_w, wk_w, wv_w, wo_w, xb, wb, maskbuf, flagsbuf);

    gemm_qkv<<<dim3(24, 32), 256, 0, stream>>>(xb, wqb, wkb, wvb,
                                               wq_b, wk_b, wv_b, qbuf, kbuf, vbuf);

    attn_kernel<<<1024, 256, 0, stream>>>(qbuf, kbuf, vbuf, maskbuf, flagsbuf,
                                          o_part, mlbuf);

    combine_kernel<<<4096, 256, 0, stream>>>(o_part, mlbuf, attnout);

    gemm_proj<<<dim3(8, 64), 256, 0, stream>>>(attnout, wob, wo_b, out);
}

// Round 9
// 232.742 us; speedup vs baseline: 1.3319x; 1.3319x over previous
//
#include <hip/hip_runtime.h>
#include <hip/hip_bf16.h>

typedef short short8 __attribute__((ext_vector_type(8)));
typedef float f32x4 __attribute__((ext_vector_type(4)));

#define MFMA32(a, b, c) __builtin_amdgcn_mfma_f32_16x16x32_bf16(a, b, c, 0, 0, 0)

#if __has_builtin(__builtin_amdgcn_exp2f)
#define EXP2F(x) __builtin_amdgcn_exp2f(x)
#else
#define EXP2F(x) exp2f(x)
#endif

// async global->LDS, 16B per lane; LDS dest = wave-uniform base + lane*16
#define GLL16(gp, lp) __builtin_amdgcn_global_load_lds(                                  \
    (__attribute__((address_space(1))) unsigned int*)(unsigned long long)(const void*)(gp), \
    (__attribute__((address_space(3))) unsigned int*)(lp), 16, 0, 0)

// fp32 -> bf16 RNE
__device__ __forceinline__ unsigned short f2b(float f) {
    union { float f; unsigned int u; } v;
    v.f = f;
    unsigned int u = v.u;
    return (unsigned short)((u + 0x7fffu + ((u >> 16) & 1u)) >> 16);
}

static __device__ __forceinline__ f32x4 max4(f32x4 x, f32x4 y) {
    f32x4 r;
    r[0] = fmaxf(x[0], y[0]); r[1] = fmaxf(x[1], y[1]);
    r[2] = fmaxf(x[2], y[2]); r[3] = fmaxf(x[3], y[3]);
    return r;
}

// ---------------- merged cvt: x (+mask) and 4 weights ----------------
__global__ void cvt_all(const float* __restrict__ x,
                        const float* __restrict__ w0, const float* __restrict__ w1,
                        const float* __restrict__ w2, const float* __restrict__ w3,
                        unsigned short* __restrict__ xb, unsigned short* __restrict__ wb,
                        float* __restrict__ maskbuf) {
    int blk = blockIdx.x;
    if (blk < 4096) {
        int i = blk * 256 + threadIdx.x;           // 0..1048575 float4s
        float4 v = ((const float4*)x)[i];
        ushort4 o;
        o.x = f2b(v.x); o.y = f2b(v.y); o.z = f2b(v.z); o.w = f2b(v.w);
        ((ushort4*)xb)[i] = o;
        if ((i & 255) == 0)
            maskbuf[i >> 8] = (v.x != 0.0f) ? 0.0f : -1e30f;
    } else {
        int wi = blk - 4096;
        int widx = wi >> 10;
        int i = (wi & 1023) * 256 + threadIdx.x;   // 0..262143 float4s
        const float* src = widx == 0 ? w0 : (widx == 1 ? w1 : (widx == 2 ? w2 : w3));
        float4 v = ((const float4*)src)[i];
        ushort4 o;
        o.x = f2b(v.x); o.y = f2b(v.y); o.z = f2b(v.z); o.w = f2b(v.w);
        ((ushort4*)(wb + ((size_t)widx << 20)))[i] = o;
    }
}

// fold softmax scale (Dh^-0.5) and log2(e) into Q so attn uses raw exp2
#define QSCALE (0.125f * 1.44269504088896341f)

// ---------------- fused QKV GEMM, dbuf, operand-swapped epilogues ----------------
// grid (24, 32): seg = blockIdx.x>>3 (0=Q,1=K,2=V).
// Q,K out: (B,H,T,64) bf16, Q pre-scaled. V out tiled:
// [combo][kb128][chunk16][d64][8keys]; key order within each 32-group:
// pos = q*8 + t*4 + i for key 16t+4q+i (PV B-frag order).
__global__ __launch_bounds__(256) void gemm_qkv(
        const unsigned short* __restrict__ A,
        const unsigned short* __restrict__ wq, const unsigned short* __restrict__ wk,
        const unsigned short* __restrict__ wv,
        const float* __restrict__ bq, const float* __restrict__ bk,
        const float* __restrict__ bv,
        unsigned short* __restrict__ qbuf, unsigned short* __restrict__ kbuf,
        unsigned short* __restrict__ vbuf) {
    __shared__ __attribute__((aligned(16))) unsigned short As[2][128 * 32];
    __shared__ __attribute__((aligned(16))) unsigned short Bs[2][128 * 32];
    int tid = threadIdx.x;
    int lane = tid & 63, wave = tid >> 6;
    int lane15 = lane & 15, quad = lane >> 4;
    int seg = blockIdx.x >> 3;
    int bn = (blockIdx.x & 7) * 128;
    int bm = blockIdx.y * 128;
    const unsigned short* Bw = seg == 0 ? wq : (seg == 1 ? wk : wv);
    const float* bias = seg == 0 ? bq : (seg == 1 ? bk : bv);
    int wm = (wave >> 1) * 64, wn = (wave & 1) * 64;

    f32x4 acc[4][4];
#pragma unroll
    for (int i = 0; i < 4; i++)
#pragma unroll
        for (int j = 0; j < 4; j++) acc[i][j] = (f32x4){0.f, 0.f, 0.f, 0.f};

    int arow = tid >> 2, acol = (tid & 3) * 8;
    const unsigned short* A0 = &A[(size_t)(bm + arow) * 1024 + acol];
    const unsigned short* A1 = A0 + (size_t)64 * 1024;
    const unsigned short* B0 = &Bw[(size_t)(bn + arow) * 1024 + acol];
    const unsigned short* B1 = B0 + (size_t)64 * 1024;

    GLL16(A0, &As[0][(size_t)tid * 8]);
    GLL16(A1, &As[0][(size_t)(tid + 256) * 8]);
    GLL16(B0, &Bs[0][(size_t)tid * 8]);
    GLL16(B1, &Bs[0][(size_t)(tid + 256) * 8]);

    // rows-operand (C rows = its index): weights for Q/K, activations for V
    int rb = (seg == 2) ? wm : wn;
    int cb = (seg == 2) ? wn : wm;

    for (int it = 0; it < 32; it++) {
        int cur = it & 1;
        __syncthreads();
        if (it < 31) {
            int kn = (it + 1) * 32;
            GLL16(A0 + kn, &As[cur ^ 1][(size_t)tid * 8]);
            GLL16(A1 + kn, &As[cur ^ 1][(size_t)(tid + 256) * 8]);
            GLL16(B0 + kn, &Bs[cur ^ 1][(size_t)tid * 8]);
            GLL16(B1 + kn, &Bs[cur ^ 1][(size_t)(tid + 256) * 8]);
        }
        const unsigned short* rs = (seg == 2) ? As[cur] : Bs[cur];
        const unsigned short* cs = (seg == 2) ? Bs[cur] : As[cur];
        short8 rf[4], cf[4];
#pragma unroll
        for (int i = 0; i < 4; i++)
            rf[i] = *(const short8*)&rs[(rb + i * 16 + lane15) * 32 + quad * 8];
#pragma unroll
        for (int j = 0; j < 4; j++)
            cf[j] = *(const short8*)&cs[(cb + j * 16 + lane15) * 32 + quad * 8];
#pragma unroll
        for (int i = 0; i < 4; i++)
#pragma unroll
            for (int j = 0; j < 4; j++)
                acc[i][j] = MFMA32(rf[i], cf[j], acc[i][j]);
    }

    int bb = bm >> 11;
    if (seg == 2) {
        // rows = m (t), cols = n (d): lane has 4 consecutive t
#pragma unroll
        for (int j = 0; j < 4; j++) {
            int nl = bn + wn + j * 16 + lane15;
            int h = nl >> 6, d = nl & 63;
            float bv_ = bias[nl];
            size_t vbase = (size_t)(bb * 16 + h) * 131072;
#pragma unroll
            for (int i = 0; i < 4; i++) {
                int tk0 = (bm & 2047) + wm + i * 16 + quad * 4;
                int B7 = tk0 >> 7, g2 = (tk0 >> 5) & 3;
                ushort4 pk;
                pk.x = f2b(acc[i][j][0] + bv_);
                pk.y = f2b(acc[i][j][1] + bv_);
                pk.z = f2b(acc[i][j][2] + bv_);
                pk.w = f2b(acc[i][j][3] + bv_);
                size_t off = vbase + (size_t)(((B7 * 16 + g2 * 4 + quad) * 64 + d)) * 8
                             + (i & 1) * 4;
                *(ushort4*)&vbuf[off] = pk;
            }
        }
    } else {
        // rows = n (d), cols = m (t): lane has 4 consecutive d -> ushort4 along d
#pragma unroll
        for (int i = 0; i < 4; i++) {
            int n0 = bn + wn + i * 16 + quad * 4;
            int h = n0 >> 6, d0 = n0 & 63;
            f32x4 bv4 = *(const f32x4*)&bias[n0];
            unsigned short* dst = (seg == 0) ? qbuf : kbuf;
#pragma unroll
            for (int j = 0; j < 4; j++) {
                int m = bm + wm + j * 16 + lane15;
                int tk = m & 2047;
                f32x4 v = acc[i][j] + bv4;
                ushort4 pk;
                if (seg == 0) {
                    pk.x = f2b(v[0] * QSCALE); pk.y = f2b(v[1] * QSCALE);
                    pk.z = f2b(v[2] * QSCALE); pk.w = f2b(v[3] * QSCALE);
                } else {
                    pk.x = f2b(v[0]); pk.y = f2b(v[1]);
                    pk.z = f2b(v[2]); pk.w = f2b(v[3]);
                }
                *(ushort4*)&dst[((size_t)((bb * 16 + h) * 2048 + tk)) * 64 + d0] = pk;
            }
        }
    }
}

// ---------------- output projection GEMM: 64x128 tiles, dbuf, float4 stores ----------------
__global__ __launch_bounds__(256) void gemm_proj(
        const unsigned short* __restrict__ A, const unsigned short* __restrict__ Bw,
        const float* __restrict__ bias, float* __restrict__ out) {
    __shared__ __attribute__((aligned(16))) unsigned short As[2][64 * 32];
    __shared__ __attribute__((aligned(16))) unsigned short Bs[2][128 * 32];
    int tid = threadIdx.x;
    int lane = tid & 63, wave = tid >> 6;
    int lane15 = lane & 15, quad = lane >> 4;
    int bn = blockIdx.x * 128, bm = blockIdx.y * 64;
    int wm = (wave >> 1) * 32, wn = (wave & 1) * 64;

    f32x4 acc[4][2];
#pragma unroll
    for (int i = 0; i < 4; i++)
#pragma unroll
        for (int j = 0; j < 2; j++) acc[i][j] = (f32x4){0.f, 0.f, 0.f, 0.f};

    int arow = tid >> 2, acol = (tid & 3) * 8;
    const unsigned short* A0 = &A[(size_t)(bm + arow) * 1024 + acol];
    const unsigned short* B0 = &Bw[(size_t)(bn + arow) * 1024 + acol];
    const unsigned short* B1 = B0 + (size_t)64 * 1024;

    GLL16(A0, &As[0][(size_t)tid * 8]);
    GLL16(B0, &Bs[0][(size_t)tid * 8]);
    GLL16(B1, &Bs[0][(size_t)(tid + 256) * 8]);

    for (int it = 0; it < 32; it++) {
        int cur = it & 1;
        __syncthreads();
        if (it < 31) {
            int kn = (it + 1) * 32;
            GLL16(A0 + kn, &As[cur ^ 1][(size_t)tid * 8]);
            GLL16(B0 + kn, &Bs[cur ^ 1][(size_t)tid * 8]);
            GLL16(B1 + kn, &Bs[cur ^ 1][(size_t)(tid + 256) * 8]);
        }
        const unsigned short* as = As[cur];
        const unsigned short* bs = Bs[cur];
        short8 af[2], bf[4];
#pragma unroll
        for (int j = 0; j < 2; j++)
            af[j] = *(const short8*)&as[(wm + j * 16 + lane15) * 32 + quad * 8];
#pragma unroll
        for (int i = 0; i < 4; i++)
            bf[i] = *(const short8*)&bs[(wn + i * 16 + lane15) * 32 + quad * 8];
#pragma unroll
        for (int i = 0; i < 4; i++)
#pragma unroll
            for (int j = 0; j < 2; j++)
                acc[i][j] = MFMA32(bf[i], af[j], acc[i][j]);   // rows = n
    }

#pragma unroll
    for (int i = 0; i < 4; i++) {
        int n0 = bn + wn + i * 16 + quad * 4;
        f32x4 bv4 = *(const f32x4*)&bias[n0];
#pragma unroll
        for (int j = 0; j < 2; j++) {
            int m = bm + wm + j * 16 + lane15;
            f32x4 v = acc[i][j] + bv4;
            *(f32x4*)&out[(size_t)m * 1024 + n0] = v;
        }
    }
}

// ---------------- flash attention v9: R5 inner loop + grid-level split-K(2) ----------------
// 1024 blocks at __launch_bounds__(256,2) (the proven no-spill allocation;
// occupancy rises via grid size: VGPR 104 -> 4 waves/SIMD, LDS 32KB -> 4 blocks/CU).
// id = c_hi(2) | half(1) | qt(4) | c_lo(3). Each block: 128 q x 1024 keys.
// Partials: normalized O (bf16) + (m,l); combine kernel merges halves.
__global__ __launch_bounds__(256, 2) void attn_kernel(
        const unsigned short* __restrict__ qbuf, const unsigned short* __restrict__ kbuf,
        const unsigned short* __restrict__ vtbuf, const float* __restrict__ maskbuf,
        unsigned short* __restrict__ o_part, float2* __restrict__ mlbuf) {
    __shared__ __attribute__((aligned(16))) unsigned short Ks[2][128 * 64];

    int id = blockIdx.x;
    int c_lo = id & 7;
    int qt = (id >> 3) & 15;
    int half = (id >> 7) & 1;
    int c_hi = id >> 8;
    int combo = c_lo | (c_hi << 3);
    int b = combo >> 4;
    int tid = threadIdx.x, lane = tid & 63, wave = tid >> 6;
    int lane15 = lane & 15, quad = lane >> 4;
    int q0 = qt * 128 + wave * 32;
    int kb0 = half * 1024;

    const unsigned short* Q  = qbuf  + (size_t)combo * 2048 * 64;
    const unsigned short* Kp = kbuf  + (size_t)combo * 2048 * 64;
    const unsigned short* Vt = vtbuf + (size_t)combo * 131072;   // tiled
    const float* mb = maskbuf + b * 2048;

    short8 qf[2][2];
#pragma unroll
    for (int a = 0; a < 2; a++)
#pragma unroll
        for (int g = 0; g < 2; g++)
            qf[a][g] = *(const short8*)&Q[(size_t)(q0 + a * 16 + lane15) * 64 + g * 32 + quad * 8];

    float m_run[2] = {-1e30f, -1e30f}, l_run[2] = {0.f, 0.f};
    f32x4 o[2][4];
#pragma unroll
    for (int a = 0; a < 2; a++)
#pragma unroll
        for (int c = 0; c < 4; c++) o[a][c] = (f32x4){0.f, 0.f, 0.f, 0.f};

    const f32x4 z4 = {0.f, 0.f, 0.f, 0.f};
    int x7 = lane15 & 7;

    // prologue: stage first K tile of this half
#pragma unroll
    for (int r4 = 0; r4 < 4; r4++) {
        int ci = tid + r4 * 256;
        int kr = ci >> 3, kc = (ci & 7) ^ (kr & 7);
        GLL16(&Kp[(size_t)(kb0 + kr) * 64 + kc * 8], &Ks[0][(size_t)ci * 8]);
    }

    for (int it = 0; it < 8; it++) {
        int cur = it & 1;
        int kb = kb0 + it * 128;
        __syncthreads();                       // K[cur] staged; prior-iter reads drained

        // ---- S^T = K.Q^T : 8 key-tiles x 2 q-tiles ----
        const unsigned short* ks = Ks[cur];
        f32x4 s[2][8];
#pragma unroll
        for (int t = 0; t < 8; t++) {
            int row = t * 16 + lane15;
            short8 k0 = *(const short8*)&ks[row * 64 + (quad ^ x7) * 8];
            short8 k1 = *(const short8*)&ks[row * 64 + ((quad + 4) ^ x7) * 8];
            s[0][t] = MFMA32(k1, qf[0][1], MFMA32(k0, qf[0][0], z4));
            s[1][t] = MFMA32(k1, qf[1][1], MFMA32(k0, qf[1][0], z4));
        }

        // ---- all V fragments for this iter (consumed at PV; softmax hides latency) ----
        short8 vv[16];
#pragma unroll
        for (int c = 0; c < 4; c++)
#pragma unroll
            for (int g = 0; g < 4; g++)
                vv[c * 4 + g] = *(const short8*)&Vt[
                    (size_t)((((half * 8 + it) * 16 + g * 4 + quad) * 64)
                             + c * 16 + lane15) * 8];

        // ---- prefetch next K tile ----
        if (it < 7) {
#pragma unroll
            for (int r4 = 0; r4 < 4; r4++) {
                int ci = tid + r4 * 256;
                int kr = ci >> 3, kc = (ci & 7) ^ (kr & 7);
                GLL16(&Kp[(size_t)(kb + 128 + kr) * 64 + kc * 8],
                      &Ks[cur ^ 1][(size_t)ci * 8]);
            }
        }

        // ---- mask (additive -1e30; scores already in log2 domain) ----
#pragma unroll
        for (int t = 0; t < 8; t++) {
            f32x4 mkt = *(const f32x4*)&mb[kb + t * 16 + quad * 4];
            s[0][t] += mkt;
            s[1][t] += mkt;
        }

        // ---- online softmax + pack P into MFMA32 B-frags ----
        short8 pb8[2][4];
#pragma unroll
        for (int a = 0; a < 2; a++) {
            f32x4 m01 = max4(s[a][0], s[a][1]), m23 = max4(s[a][2], s[a][3]);
            f32x4 m45 = max4(s[a][4], s[a][5]), m67 = max4(s[a][6], s[a][7]);
            f32x4 m4 = max4(max4(m01, m23), max4(m45, m67));
            float mx = fmaxf(fmaxf(m4[0], m4[1]), fmaxf(m4[2], m4[3]));
            mx = fmaxf(mx, __shfl_xor(mx, 16));
            mx = fmaxf(mx, __shfl_xor(mx, 32));
            float mnew = fmaxf(m_run[a], mx);
            float alpha = EXP2F(m_run[a] - mnew);
            m_run[a] = mnew;
            float ls = 0.f;
#pragma unroll
            for (int g = 0; g < 4; g++) {
                float e0 = EXP2F(s[a][2 * g][0] - mnew);
                float e1 = EXP2F(s[a][2 * g][1] - mnew);
                float e2 = EXP2F(s[a][2 * g][2] - mnew);
                float e3 = EXP2F(s[a][2 * g][3] - mnew);
                float f0 = EXP2F(s[a][2 * g + 1][0] - mnew);
                float f1 = EXP2F(s[a][2 * g + 1][1] - mnew);
                float f2 = EXP2F(s[a][2 * g + 1][2] - mnew);
                float f3 = EXP2F(s[a][2 * g + 1][3] - mnew);
                ls += ((e0 + e1) + (e2 + e3)) + ((f0 + f1) + (f2 + f3));
                union { uint4 u; short8 sv; } pu;   // bf16 truncation pack (P in [0,1])
                pu.u.x = __builtin_amdgcn_perm(__float_as_uint(e1), __float_as_uint(e0), 0x07060302u);
                pu.u.y = __builtin_amdgcn_perm(__float_as_uint(e3), __float_as_uint(e2), 0x07060302u);
                pu.u.z = __builtin_amdgcn_perm(__float_as_uint(f1), __float_as_uint(f0), 0x07060302u);
                pu.u.w = __builtin_amdgcn_perm(__float_as_uint(f3), __float_as_uint(f2), 0x07060302u);
                pb8[a][g] = pu.sv;
            }
            l_run[a] = l_run[a] * alpha + ls;
#pragma unroll
            for (int c = 0; c < 4; c++) o[a][c] *= alpha;
        }

        // ---- PV: each V fragment feeds both q-tiles ----
#pragma unroll
        for (int c = 0; c < 4; c++)
#pragma unroll
            for (int g = 0; g < 4; g++) {
                o[0][c] = MFMA32(vv[c * 4 + g], pb8[0][g], o[0][c]);
                o[1][c] = MFMA32(vv[c * 4 + g], pb8[1][g], o[1][c]);
            }
    }

    // ---- epilogue: normalized partial O (bf16) + (m,l) ----
#pragma unroll
    for (int a = 0; a < 2; a++) {
        float l = l_run[a];
        l += __shfl_xor(l, 16);
        l += __shfl_xor(l, 32);
        float rl = 1.0f / l;
        int q = q0 + a * 16 + lane15;
        size_t base = ((size_t)(half * 32 + combo) * 2048 + q) * 64 + quad * 4;
#pragma unroll
        for (int c = 0; c < 4; c++) {
            ushort4 pk;
            pk.x = f2b(o[a][c][0] * rl);
            pk.y = f2b(o[a][c][1] * rl);
            pk.z = f2b(o[a][c][2] * rl);
            pk.w = f2b(o[a][c][3] * rl);
            *(ushort4*)&o_part[base + c * 16] = pk;
        }
        if (quad == 0)
            mlbuf[(size_t)(half * 32 + combo) * 2048 + q] = make_float2(m_run[a], l);
    }
}

// ---------------- combine split-K halves -> attnout (B,T,C) bf16 ----------------
__global__ __launch_bounds__(256) void combine_kernel(
        const unsigned short* __restrict__ o_part, const float2* __restrict__ mlbuf,
        unsigned short* __restrict__ attnout) {
    int e4 = blockIdx.x * 256 + threadIdx.x;   // 0..1048575 ushort4 units
    int d4 = e4 & 15;
    int q = (e4 >> 4) & 2047;
    int combo = e4 >> 15;
    int b = combo >> 4, h = combo & 15;

    float2 ml0 = mlbuf[(size_t)combo * 2048 + q];
    float2 ml1 = mlbuf[(size_t)(32 + combo) * 2048 + q];
    float M = fmaxf(ml0.x, ml1.x);
    float w0 = ml0.y * EXP2F(ml0.x - M);
    float w1 = ml1.y * EXP2F(ml1.x - M);
    float inv = 1.0f / (w0 + w1);
    w0 *= inv; w1 *= inv;

    ushort4 a0 = ((const ushort4*)o_part)[((size_t)combo * 2048 + q) * 16 + d4];
    ushort4 a1 = ((const ushort4*)o_part)[((size_t)(32 + combo) * 2048 + q) * 16 + d4];
    ushort4 pk;
    pk.x = f2b(w0 * __uint_as_float((unsigned)a0.x << 16) + w1 * __uint_as_float((unsigned)a1.x << 16));
    pk.y = f2b(w0 * __uint_as_float((unsigned)a0.y << 16) + w1 * __uint_as_float((unsigned)a1.y << 16));
    pk.z = f2b(w0 * __uint_as_float((unsigned)a0.z << 16) + w1 * __uint_as_float((unsigned)a1.z << 16));
    pk.w = f2b(w0 * __uint_as_float((unsigned)a0.w << 16) + w1 * __uint_as_float((unsigned)a1.w << 16));
    ((ushort4*)attnout)[((size_t)(b * 2048 + q) * 256) + h * 16 + d4] = pk;
}

extern "C" void kernel_launch(void* const* d_in, const int* in_sizes, int n_in,
                              void* d_out, int out_size, void* d_ws, size_t ws_size,
                              hipStream_t stream) {
    const float* x    = (const float*)d_in[0];
    const float* wq_w = (const float*)d_in[1];
    const float* wq_b = (const float*)d_in[2];
    const float* wk_w = (const float*)d_in[3];
    const float* wk_b = (const float*)d_in[4];
    const float* wv_w = (const float*)d_in[5];
    const float* wv_b = (const float*)d_in[6];
    const float* wo_w = (const float*)d_in[7];
    const float* wo_b = (const float*)d_in[8];
    float* out = (float*)d_out;

    char* ws = (char*)d_ws;
    size_t off = 0;
    unsigned short* xb      = (unsigned short*)(ws + off); off += (size_t)4096 * 1024 * 2;
    unsigned short* wb      = (unsigned short*)(ws + off); off += (size_t)4 * 1024 * 1024 * 2;
    unsigned short* qbuf    = (unsigned short*)(ws + off); off += (size_t)4096 * 1024 * 2;
    unsigned short* kbuf    = (unsigned short*)(ws + off); off += (size_t)4096 * 1024 * 2;
    unsigned short* vbuf    = (unsigned short*)(ws + off); off += (size_t)4096 * 1024 * 2;
    unsigned short* attnout = (unsigned short*)(ws + off); off += (size_t)4096 * 1024 * 2;
    unsigned short* o_part  = (unsigned short*)(ws + off); off += (size_t)2 * 32 * 2048 * 64 * 2;
    float2* mlbuf           = (float2*)(ws + off);         off += (size_t)2 * 32 * 2048 * 8;
    float* maskbuf          = (float*)(ws + off);          off += 4096 * 4;

    unsigned short* wqb = wb;
    unsigned short* wkb = wb + (1u << 20);
    unsigned short* wvb = wb + (2u << 20);
    unsigned short* wob = wb + (3u << 20);

    cvt_all<<<8192, 256, 0, stream>>>(x, wq_w, wk_w, wv_w, wo_w, xb, wb, maskbuf);

    gemm_qkv<<<dim3(24, 32), 256, 0, stream>>>(xb, wqb, wkb, wvb,
                                               wq_b, wk_b, wv_b, qbuf, kbuf, vbuf);

    attn_kernel<<<1024, 256, 0, stream>>>(qbuf, kbuf, vbuf, maskbuf, o_part, mlbuf);

    combine_kernel<<<4096, 256, 0, stream>>>(o_part, mlbuf, attnout);

    gemm_proj<<<dim3(8, 64), 256, 0, stream>>>(attnout, wob, wo_b, out);
}